// Round 13
// baseline (85.414 us; speedup 1.0000x reference)
//
#include <hip/hip_runtime.h>
#include <hip/hip_bf16.h>

#define NL  128   // layers (n)
#define DK  256   // d_in (k)
#define DO_ 256   // d_out (o)
#define MB  1024  // batch (m)

typedef __attribute__((ext_vector_type(4))) float f32x4;
typedef __attribute__((ext_vector_type(8))) short bf16x8;
typedef __attribute__((ext_vector_type(8))) unsigned short u16x8;
typedef __attribute__((ext_vector_type(4))) unsigned short u16x4;

static __device__ __forceinline__ unsigned short f2bf(float f) {
  __hip_bfloat16 h = __float2bfloat16(f);
  return __builtin_bit_cast(unsigned short, h);
}

// ---------------------------------------------------------------------------
// Prep: W[n][k][o] fp32 -> Wt in MFMA B-fragment order, bf16 (verified R4-R12):
//   elem offset = ((n*16+ob16)*8 + s)*512 + (lhi*16+lrow)*8 + (k&7)
// so a wave's B-load for (ob16, s) is ONE contiguous 1KB dwordx4 per lane.
// ---------------------------------------------------------------------------
__global__ __launch_bounds__(256) void wt_prep(const float* __restrict__ W,
                                               unsigned short* __restrict__ Wt) {
  const int n     = blockIdx.y;
  const int ktile = (blockIdx.x >> 2) * 64;
  const int otile = (blockIdx.x & 3) * 64;
  __shared__ float tile[64][65];  // +1 pad: conflict-free column reads
  const float* Wn = W + (size_t)n * DK * DO_;
  const int t  = threadIdx.x;
  const int lr = t >> 4;
  const int lc = (t & 15) * 4;
#pragma unroll
  for (int p = 0; p < 4; ++p) {
    const int k = p * 16 + lr;
    const float4 v = *(const float4*)(Wn + (size_t)(ktile + k) * DO_ + otile + lc);
    tile[k][lc + 0] = v.x; tile[k][lc + 1] = v.y;
    tile[k][lc + 2] = v.z; tile[k][lc + 3] = v.w;
  }
  __syncthreads();
  const int ol = t >> 2;            // local o 0..63
  const int o  = otile + ol;
  const int kq = t & 3;
  unsigned short* Wt_n = Wt + (size_t)n * DO_ * DK;
#pragma unroll
  for (int h = 0; h < 2; ++h) {
    u16x8 w;
#pragma unroll
    for (int j = 0; j < 8; ++j) w[j] = f2bf(tile[kq * 16 + h * 8 + j][ol]);
    const int kc = (ktile >> 3) + kq * 2 + h;   // global 8-k chunk id (0..31)
    const int ob = o >> 4, lrw = o & 15, s = kc >> 2, lh = kc & 3;
    *(u16x8*)(Wt_n + ((size_t)(ob * 8 + s) * 64 + lh * 16 + lrw) * 8) = w;
  }
}

// ---------------------------------------------------------------------------
// Main: n-LOOP block. Block = 32 m-rows x 8 consecutive n, 512 thr / 8 waves.
// Per m-row, x reads & out writes advance SEQUENTIALLY (+1KB/iter over an
// 8KB contiguous span) instead of isolated 1KB islands. Depth-2 pipeline:
// iter i issues loads for n=i+2 (reg), converts n=i+1 into a 3-buffer LDS
// ring (WAR-safe with ONE lgkmcnt+s_barrier per iter; vmcnt never drained),
// computes n=i (wave = (mh, ob): 16m x 64o, 32 MFMA), NT-stores n=i.
// Stage math, prefrag Wt B-loads, swapped MFMA all verified R8/R12.
// XCD n-window: wid&7 -> n in [xcd*16,+16): 2MB Wt slice per XCD L2.
// ---------------------------------------------------------------------------
__global__ __launch_bounds__(512, 4) void nlinear_mfma(
    const float* __restrict__ X, const unsigned short* __restrict__ Wt,
    const float* __restrict__ bias, float* __restrict__ out) {
  const int wid  = blockIdx.x;
  const int ng   = (wid & 7) * 2 + ((wid >> 3) & 1);  // 0..15, 8 n each
  const int mg   = wid >> 4;                          // 0..31, 32 rows each
  const int n0   = ng * 8;
  const int t    = threadIdx.x;
  const int wave = t >> 6;
  const int lane = t & 63;
  const int lrow = lane & 15;
  const int lhi  = lane >> 4;
  const int mbase = mg * 32;

  __shared__ unsigned short Alds[3][32 * 256];  // 48 KB ring, swizzled slots

  // ---- staging: wave stages rows wave*4..+3; lane takes k=lane*4 (16B) ----
  // per row, successive n are +1KB: sequential DRAM advance.
  const float* xb0 = X + ((size_t)(mbase + wave * 4 + 0) * NL + n0) * DK + lane * 4;
  const float* xb1 = X + ((size_t)(mbase + wave * 4 + 1) * NL + n0) * DK + lane * 4;
  const float* xb2 = X + ((size_t)(mbase + wave * 4 + 2) * NL + n0) * DK + lane * 4;
  const float* xb3 = X + ((size_t)(mbase + wave * 4 + 3) * NL + n0) * DK + lane * 4;

#define XLOAD(S, nn)                         \
  {                                          \
    S[0] = *(const f32x4*)(xb0 + (nn) * DK); \
    S[1] = *(const f32x4*)(xb1 + (nn) * DK); \
    S[2] = *(const f32x4*)(xb2 + (nn) * DK); \
    S[3] = *(const f32x4*)(xb3 + (nn) * DK); \
  }

  // convert + swizzled write (verified R8 math): slot c=(lane>>1) ^ (row&7)
#define CVTWRITE(b, S)                                                       \
  {                                                                          \
    char* abw = (char*)Alds[b];                                              \
    _Pragma("unroll")                                                        \
    for (int r2 = 0; r2 < 4; ++r2) {                                         \
      const int row = wave * 4 + r2;                                         \
      u16x4 h;                                                               \
      _Pragma("unroll")                                                      \
      for (int e = 0; e < 4; ++e) h[e] = f2bf(S[r2][e]);                     \
      *(u16x4*)(abw + row * 512 + (((lane >> 1) ^ (row & 7)) << 4) +         \
                (lane & 1) * 8) = h;                                         \
    }                                                                        \
  }

  // B-load: coalesced 1KB per instr from prefragmented, L2-resident Wt
#define BLOAD(Wn_, s, oj) \
  (*(const bf16x8*)((Wn_) + ((size_t)(((ob * 4 + (oj)) * 8) + (s)) * 64 + lane) * 8))

  const int mh = wave >> 2;   // m-half: rows mh*16..+16
  const int ob = wave & 3;    // o-slice of 64

  f32x4 sA[4], sB[4];
  XLOAD(sA, 0);
  XLOAD(sB, 1);
  CVTWRITE(0, sA);
  asm volatile("s_waitcnt lgkmcnt(0)" ::: "memory");
  __builtin_amdgcn_s_barrier();
  __builtin_amdgcn_sched_barrier(0);

#pragma unroll
  for (int i = 0; i < 8; ++i) {
    // (a) issue loads for n=i+2 into the freed register set
    if (i + 2 < 8) {
      if (i & 1) { XLOAD(sB, i + 2); } else { XLOAD(sA, i + 2); }
    }
    // (b) convert n=i+1 -> buf[(i+1)%3] (vmcnt waits only that set's loads)
    if (i + 1 < 8) {
      if (i & 1) { CVTWRITE((i + 1) % 3, sA); } else { CVTWRITE((i + 1) % 3, sB); }
    }
    // (c) one barrier per iter; vmcnt NOT drained (next loads stay in flight)
    asm volatile("s_waitcnt lgkmcnt(0)" ::: "memory");
    __builtin_amdgcn_s_barrier();
    __builtin_amdgcn_sched_barrier(0);

    // (d) compute n = n0+i from buf[i%3]
    const int n = n0 + i;
    const unsigned short* Wn = Wt + (size_t)n * DO_ * DK;
    const char* ab = (const char*)Alds[i % 3];

    f32x4 acc[4];
#pragma unroll
    for (int oj = 0; oj < 4; ++oj) acc[oj] = (f32x4){0.f, 0.f, 0.f, 0.f};

    // 2-deep B prefetch pipeline (static indices)
    bf16x8 bA[4], bB[4];
#pragma unroll
    for (int oj = 0; oj < 4; ++oj) bA[oj] = BLOAD(Wn, 0, oj);
#pragma unroll
    for (int oj = 0; oj < 4; ++oj) bB[oj] = BLOAD(Wn, 1, oj);

    const int row = mh * 16 + lrow;
#pragma unroll
    for (int s = 0; s < 8; ++s) {
      const bf16x8 af = *(const bf16x8*)(
          ab + row * 512 + (((s * 4 + lhi) ^ (row & 7)) << 4));
      const bool odd = (s & 1) != 0;
#pragma unroll
      for (int oj = 0; oj < 4; ++oj) {  // SWAPPED: D[o][m], lane = 4 contig o
        const bf16x8 bf = odd ? bB[oj] : bA[oj];
        acc[oj] = __builtin_amdgcn_mfma_f32_16x16x32_bf16(bf, af, acc[oj], 0, 0, 0);
      }
      if (s < 6) {
        if (odd) {
#pragma unroll
          for (int oj = 0; oj < 4; ++oj) bB[oj] = BLOAD(Wn, s + 2, oj);
        } else {
#pragma unroll
          for (int oj = 0; oj < 4; ++oj) bA[oj] = BLOAD(Wn, s + 2, oj);
        }
      }
    }

    // stores: m = mbase + mh*16 + lrow; o = ob*64 + oj*16 + lhi*4; NT f32x4
    const float* bb = bias + (size_t)n * DO_ + ob * 64 + lhi * 4;
    float* orow = out + ((size_t)(mbase + row) * NL + n) * DO_ + ob * 64 + lhi * 4;
#pragma unroll
    for (int oj = 0; oj < 4; ++oj) {
      const f32x4 bv = *(const f32x4*)(bb + oj * 16);
      const f32x4 v  = acc[oj] + bv;
      __builtin_nontemporal_store(v, (f32x4*)(orow + oj * 16));
    }
  }
#undef XLOAD
#undef CVTWRITE
#undef BLOAD
}

// ---------------------------------------------------------------------------
// Fallback (only if ws too small for Wt): plain fp32, correct but slow.
// ---------------------------------------------------------------------------
__global__ __launch_bounds__(256) void nlinear_naive(
    const float* __restrict__ X, const float* __restrict__ W,
    const float* __restrict__ B, float* __restrict__ out) {
  const int n = blockIdx.y;
  const int m = blockIdx.x;
  const int o = threadIdx.x;
  __shared__ float xs[DK];
  xs[o] = X[((size_t)m * NL + n) * DK + o];
  __syncthreads();
  const float* Wn = W + (size_t)n * DK * DO_;
  float s = B[n * DO_ + o];
  for (int k = 0; k < DK; ++k) s = fmaf(xs[k], Wn[(size_t)k * DO_ + o], s);
  out[((size_t)m * NL + n) * DO_ + o] = s;
}

extern "C" void kernel_launch(void* const* d_in, const int* in_sizes, int n_in,
                              void* d_out, int out_size, void* d_ws, size_t ws_size,
                              hipStream_t stream) {
  const float* x = (const float*)d_in[0];
  const float* w = (const float*)d_in[1];
  const float* b = (const float*)d_in[2];
  float* out     = (float*)d_out;
  const size_t wt_bytes = (size_t)NL * DK * DO_ * sizeof(unsigned short);
  if (ws_size >= wt_bytes) {
    unsigned short* wt = (unsigned short*)d_ws;
    wt_prep<<<dim3(16, NL), 256, 0, stream>>>(w, wt);
    nlinear_mfma<<<dim3(512), 512, 0, stream>>>(x, wt, b, out);
  } else {
    nlinear_naive<<<dim3(MB, NL), 256, 0, stream>>>(x, w, b, out);
  }
}

// Round 14
// 72.043 us; speedup vs baseline: 1.1856x; 1.1856x over previous
//
#include <hip/hip_runtime.h>
#include <hip/hip_bf16.h>

#define NL  128   // layers (n)
#define DK  256   // d_in (k)
#define DO_ 256   // d_out (o)
#define MB  1024  // batch (m)

typedef __attribute__((ext_vector_type(4))) float f32x4;
typedef __attribute__((ext_vector_type(8))) short bf16x8;
typedef __attribute__((ext_vector_type(8))) unsigned short u16x8;
typedef __attribute__((ext_vector_type(4))) unsigned short u16x4;

static __device__ __forceinline__ unsigned short f2bf(float f) {
  __hip_bfloat16 h = __float2bfloat16(f);
  return __builtin_bit_cast(unsigned short, h);
}

// ---------------------------------------------------------------------------
// Prep: W[n][k][o] fp32 -> Wt in MFMA B-fragment order, bf16 (verified R4-R13):
//   unit (o, kc[8-k chunk]) -> ob=o>>4, lrow=o&15, s=kc>>2, lhi=kc&3
//   elem offset = ((n*16+ob)*8 + s)*512 + (lhi*16+lrow)*8 + (k&7)
// so a wave's B-load for (ob, s) is ONE contiguous 1KB dwordx4 per lane.
// ---------------------------------------------------------------------------
__global__ __launch_bounds__(256) void wt_prep(const float* __restrict__ W,
                                               unsigned short* __restrict__ Wt) {
  const int n     = blockIdx.y;
  const int ktile = (blockIdx.x >> 2) * 64;
  const int otile = (blockIdx.x & 3) * 64;
  __shared__ float tile[64][65];  // +1 pad: conflict-free column reads
  const float* Wn = W + (size_t)n * DK * DO_;
  const int t  = threadIdx.x;
  const int lr = t >> 4;
  const int lc = (t & 15) * 4;
#pragma unroll
  for (int p = 0; p < 4; ++p) {
    const int k = p * 16 + lr;
    const float4 v = *(const float4*)(Wn + (size_t)(ktile + k) * DO_ + otile + lc);
    tile[k][lc + 0] = v.x; tile[k][lc + 1] = v.y;
    tile[k][lc + 2] = v.z; tile[k][lc + 3] = v.w;
  }
  __syncthreads();
  const int ol = t >> 2;            // local o 0..63
  const int o  = otile + ol;
  const int kq = t & 3;
  unsigned short* Wt_n = Wt + (size_t)n * DO_ * DK;
#pragma unroll
  for (int h = 0; h < 2; ++h) {
    u16x8 w;
#pragma unroll
    for (int j = 0; j < 8; ++j) w[j] = f2bf(tile[kq * 16 + h * 8 + j][ol]);
    const int kc = (ktile >> 3) + kq * 2 + h;   // global 8-k chunk id (0..31)
    const int ob = o >> 4, lrw = o & 15, s = kc >> 2, lh = kc & 3;
    *(u16x8*)(Wt_n + ((size_t)(ob * 8 + s) * 64 + lh * 16 + lrw) * 8) = w;
  }
}

// ---------------------------------------------------------------------------
// Main: EXACT R12 structure (best: 77.8 us) with ONE change — LDS-bounce
// epilogue. The swapped-MFMA acc fragments (64B granule per store instr,
// 1.28x NT write amplification in R12) are bounced through the dead 32KB
// A-LDS in two 32-row passes, then NT-stored as FULL 1KB wave-contiguous
// lines (one dwordx4 per lane per out row). Everything upstream identical.
// ---------------------------------------------------------------------------
__global__ __launch_bounds__(512, 4) void nlinear_mfma(
    const float* __restrict__ X, const unsigned short* __restrict__ Wt,
    const float* __restrict__ bias, float* __restrict__ out) {
  const int wid  = blockIdx.x;
  const int n    = (wid & 7) * 16 + ((wid >> 3) & 15);
  const int mg   = wid >> 7;          // 0..15, 64 rows each
  const int t    = threadIdx.x;
  const int wave = t >> 6;            // 0..7 = o-slice of 32
  const int lane = t & 63;
  const int lrow = lane & 15;
  const int lhi  = lane >> 4;
  const int mbase = mg * 64;

  __shared__ unsigned short Alds[64 * 256];  // 32 KB; A-tile, then epilogue tile

  // ---- stage: wave w loads rows w*8+j (j=0..7), lane takes k=lane*4 ----
  const float* xw = X + ((size_t)(mbase + wave * 8) * NL + n) * DK + lane * 4;
  f32x4 xv[8];
#pragma unroll
  for (int j = 0; j < 8; ++j)
    xv[j] = *(const f32x4*)(xw + (size_t)j * NL * DK);

  // bias: issue early, independent of everything
  const float* bb = bias + n * DO_ + wave * 32 + lhi * 4;
  f32x4 bv[2];
#pragma unroll
  for (int oj = 0; oj < 2; ++oj) bv[oj] = *(const f32x4*)(bb + oj * 16);

  char* ab = (char*)Alds;
#pragma unroll
  for (int j = 0; j < 8; ++j) {
    u16x4 h;
#pragma unroll
    for (int e = 0; e < 4; ++e) h[e] = f2bf(xv[j][e]);
    // row = wave*8+j; chunk c = lane>>1; slot = c ^ (row&7) = c ^ j  (verified)
    *(u16x4*)(ab + (wave * 8 + j) * 512 + (((lane >> 1) ^ j) << 4) + (lane & 1) * 8) = h;
  }
  __syncthreads();  // staging barrier

  const unsigned short* Wn = Wt + (size_t)n * DO_ * DK;

  f32x4 acc[4][2];
#pragma unroll
  for (int mt = 0; mt < 4; ++mt)
#pragma unroll
    for (int oj = 0; oj < 2; ++oj) acc[mt][oj] = (f32x4){0.f, 0.f, 0.f, 0.f};

  // B-load helper: coalesced 1KB per instr from prefragmented, L2-resident Wt
#define BLOAD(s, oj) \
  (*(const bf16x8*)(Wn + ((size_t)(((wave * 2 + (oj)) * 8) + (s)) * 64 + lane) * 8))

  // 2-deep explicit B prefetch pipeline (all indices compile-time: no scratch)
  bf16x8 bA0 = BLOAD(0, 0), bA1 = BLOAD(0, 1);
  bf16x8 bB0 = BLOAD(1, 0), bB1 = BLOAD(1, 1);

#pragma unroll
  for (int s = 0; s < 8; ++s) {
    const bf16x8 bc0 = (s & 1) ? bB0 : bA0;
    const bf16x8 bc1 = (s & 1) ? bB1 : bA1;
    if (s < 6) {  // refill the slot just consumed with s+2
      if (s & 1) { bB0 = BLOAD(s + 2, 0); bB1 = BLOAD(s + 2, 1); }
      else       { bA0 = BLOAD(s + 2, 0); bA1 = BLOAD(s + 2, 1); }
    }
    bf16x8 af[4];
#pragma unroll
    for (int mt = 0; mt < 4; ++mt) {
      const int row = mt * 16 + lrow;
      af[mt] = *(const bf16x8*)(ab + row * 512 + (((s * 4 + lhi) ^ (row & 7)) << 4));
    }
#pragma unroll
    for (int mt = 0; mt < 4; ++mt) {  // SWAPPED: D[o][m], lane regs = 4 contig o
      acc[mt][0] = __builtin_amdgcn_mfma_f32_16x16x32_bf16(bc0, af[mt], acc[mt][0], 0, 0, 0);
      acc[mt][1] = __builtin_amdgcn_mfma_f32_16x16x32_bf16(bc1, af[mt], acc[mt][1], 0, 0, 0);
    }
  }
#undef BLOAD

  // ---- LDS-bounce epilogue: 2 passes x 32 rows (reuses the 32KB A-LDS) ----
  // Pass p covers m-local rows p*32..+32 (global mt = p*2, p*2+1).
  // Write: thread puts acc[mt][oj]+bv at [rloc][c16 = wave*8+oj*4+lhi],
  //        swizzled slot c^(rloc&7)  (8-beat-optimal, no conflicts).
  // Read:  wave reads its 4 rows, lane takes 16B chunk lane^(rloc&7)
  //        (permutation, conflict-free) -> ONE contiguous 1KB NT store/row.
#pragma unroll
  for (int pass = 0; pass < 2; ++pass) {
    // prior readers of Alds are done (own lgkm waits precede); WAR barrier
    asm volatile("s_waitcnt lgkmcnt(0)" ::: "memory");
    __builtin_amdgcn_s_barrier();
#pragma unroll
    for (int mt2 = 0; mt2 < 2; ++mt2) {
      const int mtg  = pass * 2 + mt2;
      const int rloc = mt2 * 16 + lrow;          // 0..31
#pragma unroll
      for (int oj = 0; oj < 2; ++oj) {
        const f32x4 v = acc[mtg][oj] + bv[oj];
        const int c = wave * 8 + oj * 4 + lhi;   // 16B chunk index 0..63
        *(f32x4*)(ab + rloc * 1024 + ((c ^ (rloc & 7)) << 4)) = v;
      }
    }
    asm volatile("s_waitcnt lgkmcnt(0)" ::: "memory");
    __builtin_amdgcn_s_barrier();
    // read + NT store: wave handles rows wave*4 .. +4 of this pass
#pragma unroll
    for (int j = 0; j < 4; ++j) {
      const int rloc = wave * 4 + j;
      const int m    = mbase + pass * 32 + rloc;
      const f32x4 v  = *(const f32x4*)(ab + rloc * 1024 + ((lane ^ (rloc & 7)) << 4));
      __builtin_nontemporal_store(
          v, (f32x4*)(out + ((size_t)m * NL + n) * DO_ + lane * 4));
    }
  }
}

// ---------------------------------------------------------------------------
// Fallback (only if ws too small for Wt): plain fp32, correct but slow.
// ---------------------------------------------------------------------------
__global__ __launch_bounds__(256) void nlinear_naive(
    const float* __restrict__ X, const float* __restrict__ W,
    const float* __restrict__ B, float* __restrict__ out) {
  const int n = blockIdx.y;
  const int m = blockIdx.x;
  const int o = threadIdx.x;
  __shared__ float xs[DK];
  xs[o] = X[((size_t)m * NL + n) * DK + o];
  __syncthreads();
  const float* Wn = W + (size_t)n * DK * DO_;
  float s = B[n * DO_ + o];
  for (int k = 0; k < DK; ++k) s = fmaf(xs[k], Wn[(size_t)k * DO_ + o], s);
  out[((size_t)m * NL + n) * DO_ + o] = s;
}

extern "C" void kernel_launch(void* const* d_in, const int* in_sizes, int n_in,
                              void* d_out, int out_size, void* d_ws, size_t ws_size,
                              hipStream_t stream) {
  const float* x = (const float*)d_in[0];
  const float* w = (const float*)d_in[1];
  const float* b = (const float*)d_in[2];
  float* out     = (float*)d_out;
  const size_t wt_bytes = (size_t)NL * DK * DO_ * sizeof(unsigned short);
  if (ws_size >= wt_bytes) {
    unsigned short* wt = (unsigned short*)d_ws;
    wt_prep<<<dim3(16, NL), 256, 0, stream>>>(w, wt);
    nlinear_mfma<<<dim3(2048), 512, 0, stream>>>(x, wt, b, out);
  } else {
    nlinear_naive<<<dim3(MB, NL), 256, 0, stream>>>(x, w, b, out);
  }
}